// Round 7
// baseline (291.207 us; speedup 1.0000x reference)
//
#include <hip/hip_runtime.h>
#include <stdint.h>

#define LOG2E  1.44269504088896f
#define QSCALE (0.125f * LOG2E)   // folded into Q: sacc is already the exp2 argument

typedef float    f32x4_t  __attribute__((ext_vector_type(4)));
typedef float    f32x16_t __attribute__((ext_vector_type(16)));
typedef _Float16 f16x8_t  __attribute__((ext_vector_type(8)));
typedef _Float16 f16x2_t  __attribute__((ext_vector_type(2)));

#if __has_builtin(__builtin_amdgcn_exp2f)
#define EXP2F(x) __builtin_amdgcn_exp2f(x)
#else
#define EXP2F(x) exp2f(x)
#endif

__device__ __forceinline__ float rowsum2(f16x2_t p, float acc) {
#if __has_builtin(__builtin_amdgcn_fdot2)
  return __builtin_amdgcn_fdot2(p, (f16x2_t){(_Float16)1.0f, (_Float16)1.0f}, acc, false);
#else
  return acc + (float)p[0] + (float)p[1];
#endif
}

__device__ __forceinline__ int sigf(int n) {            // swap bits 2,3 (involution)
  return (n & 0x13) | ((n >> 1) & 4) | ((n << 1) & 8);
}

// ---------------- fused prep: mask scan + K/V -> fragment-major f16 ----------------
// Kf tile layout (8 KB per 64-key tile): chunk[(kb*4+kh)*2+h2][n] = 8 f16,
//   element = K[head][kbase + kb*32 + sig(n)][kh*16 + 8*h2 + j]  (sig pre-applied)
// Vf tile layout: chunk[(f*2+vh)*64 + l] = 8 f16,
//   element = V[head][kbase + f*16 + 8*(l>>5) + j][(l&31) + 32*vh]
// => every sdpa fragment load is one fully-coalesced dwordx4 (64 lanes x 16B contiguous).
__global__ void prep_kernel(const float* __restrict__ M, const float* __restrict__ K,
                            const float* __restrict__ V, _Float16* __restrict__ Kf,
                            _Float16* __restrict__ Vf, int* __restrict__ flag) {
  __shared__ __align__(16) _Float16 T[64 * 72];
  const int tid = threadIdx.x;
  const int bid = blockIdx.x;

  // -- mask all-zero scan (67 MB total) --
  {
    const float* p = M + (size_t)bid * 8192 + (size_t)tid * 4;
    unsigned acc = 0;
#pragma unroll
    for (int i = 0; i < 8; ++i) {
      f32x4_t v = *(const f32x4_t*)(p + (size_t)i * 1024);
      acc |= __float_as_uint(v[0]) | __float_as_uint(v[1]) |
             __float_as_uint(v[2]) | __float_as_uint(v[3]);
    }
    if (acc & 0x7fffffffu) atomicOr(flag, 1);
  }

  if (Kf != nullptr) {
    // -- K f32 -> fragment-major f16 (one 8-feat octet per thread) --
    {
      const size_t flat8 = ((size_t)bid * 256 + tid) * 8;
      const int head = (int)(flat8 >> 18);
      const int rem  = (int)(flat8 & 0x3FFFF);
      const int key  = rem >> 6;
      const int o    = (rem >> 3) & 7;
      const int kt   = key >> 6;
      const int kb   = (key >> 5) & 1;
      const int nn   = sigf(key & 31);
      const int kh   = o >> 1;
      const int h2o  = o & 1;
      f32x4_t a = *(const f32x4_t*)(K + flat8);
      f32x4_t b = *(const f32x4_t*)(K + flat8 + 4);
      union { _Float16 h[8]; uint4 q; } U;
#pragma unroll
      for (int j = 0; j < 4; ++j) { U.h[j] = (_Float16)a[j]; U.h[4 + j] = (_Float16)b[j]; }
      const size_t chunk = (size_t)(head * 64 + kt) * 512 + (size_t)((kb * 8 + kh * 2 + h2o) * 32 + nn);
      *(uint4*)(Kf + chunk * 8) = U.q;
    }
    // -- V -> fragment-major f16, one 64x64 tile per block (blocks 0..1023) --
    if (bid < 1024) {
      const int head = bid >> 6;
      const int st   = bid & 63;
      const size_t hoff = (size_t)head * 4096 * 64;
      const int sl    = tid >> 2;
      const int fbase = (tid & 3) * 16;
      const float* src = V + hoff + (size_t)(st * 64 + sl) * 64 + fbase;
#pragma unroll
      for (int c = 0; c < 4; ++c) {
        f32x4_t a = *(const f32x4_t*)(src + c * 4);
#pragma unroll
        for (int j = 0; j < 4; ++j) T[(fbase + c * 4 + j) * 72 + sl] = (_Float16)a[j];
      }
      __syncthreads();
      const int f  = tid >> 6;
      const int l  = tid & 63;
      const int nn = l & 31;
      const int hl = l >> 5;
      const size_t tbase = (size_t)(head * 64 + st) * 512;
#pragma unroll
      for (int vh = 0; vh < 2; ++vh) {
        uint4 r = *(const uint4*)&T[(nn + 32 * vh) * 72 + f * 16 + 8 * hl];
        *(uint4*)(Vf + (tbase + (size_t)((f * 2 + vh) * 64 + l)) * 8) = r;
      }
    }
  }
}

// ---------------- SDPA core: barrier-free, LDS-free, fragment-direct ----------------
// sigma trick: sig is pre-applied in Kf so PV A-fragments are lane-local sacc regs.
// Per tile: 16 coalesced dwordx4 loads (immediate offsets off 2 base pointers)
// + 16 MFMA + softmax. No __syncthreads anywhere -> compiler pipelines loads across
// tiles with counted vmcnt. K/V re-read per wave, L1/L2-resident (2 heads/XCD = 2MB < 4MB L2).
template <int NS>
__launch_bounds__(256, 4)
__global__ void sdpa_direct(const float* __restrict__ Qg, const float* __restrict__ Mg,
                            const _Float16* __restrict__ Kf, const _Float16* __restrict__ Vf,
                            float* __restrict__ Og, float* __restrict__ Opart,
                            float* __restrict__ Lpart, const int* __restrict__ flag) {
  constexpr int QTSH = (NS == 1) ? 4 : (NS == 2) ? 5 : 6;

  const int tid  = threadIdx.x;
  const int bid  = blockIdx.x;
  const int hh   = ((bid & 7) << 1) | ((bid >> 3) & 1);   // 2 heads per XCD (bid%8 -> XCD)
  const int part = (NS == 1) ? 0 : ((bid >> 4) & (NS - 1));
  const int qt   = bid >> QTSH;
  const int w    = tid >> 6;
  const int lane = tid & 63;
  const int n    = lane & 31;
  const int h2   = lane >> 5;
  const bool has_mask = (*flag) != 0;

  const size_t hoff = (size_t)hh * 4096 * 64;
  const int qcol = qt * 128 + w * 32 + n;
  const int ktn  = 64 / NS;
  const int ktlo = part * ktn;

  // ---- Q B-fragment straight from f32 ----
  f16x8_t qf[4];
  {
    const float* qp = Qg + hoff + (size_t)qcol * 64 + 8 * h2;
#pragma unroll
    for (int kh = 0; kh < 4; ++kh) {
      f32x4_t a = *(const f32x4_t*)(qp + kh * 16);
      f32x4_t b = *(const f32x4_t*)(qp + kh * 16 + 4);
      union { _Float16 h[8]; f16x8_t v; } U;
#pragma unroll
      for (int j = 0; j < 4; ++j) { U.h[j] = (_Float16)(a[j] * QSCALE); U.h[4 + j] = (_Float16)(b[j] * QSCALE); }
      qf[kh] = U.v;
    }
  }

  f32x16_t o0 = {0.f,0.f,0.f,0.f,0.f,0.f,0.f,0.f,0.f,0.f,0.f,0.f,0.f,0.f,0.f,0.f};
  f32x16_t o1 = o0;
  float lacc = 0.0f;

  // per-lane fragment base pointers; all 16 per-tile loads are immediate offsets off these
  const _Float16* ktile = Kf + (size_t)(hh * 64 + ktlo) * 4096 + h2 * 256 + n * 8;
  const _Float16* vtile = Vf + (size_t)(hh * 64 + ktlo) * 4096 + (size_t)lane * 8;

#pragma unroll 1
  for (int kk = 0; kk < ktn; ++kk) {
    const int kbase = (ktlo + kk) * 64;

    // -- mask tile: element (kb, reg=8a+4b+c) -> key kb*32 + 16a + 8*h2 + 4b + c --
    f32x4_t mk[2][2][2];
    if (has_mask) {
      const float* mp = Mg + (size_t)qcol * 4096 + kbase + 8 * h2;
#pragma unroll
      for (int kb = 0; kb < 2; ++kb)
#pragma unroll
        for (int a = 0; a < 2; ++a)
#pragma unroll
          for (int b = 0; b < 2; ++b)
            mk[kb][a][b] = *(const f32x4_t*)(mp + kb * 32 + 16 * a + 4 * b);
    }

#pragma unroll
    for (int kb = 0; kb < 2; ++kb) {
      // ---- S^T = K.Q^T, A-rows sigma-permuted via Kf layout ----
      f32x16_t acc = {0.f,0.f,0.f,0.f,0.f,0.f,0.f,0.f,0.f,0.f,0.f,0.f,0.f,0.f,0.f,0.f};
#pragma unroll
      for (int kh = 0; kh < 4; ++kh) {
        const f16x8_t ka = *(const f16x8_t*)(ktile + kb * 2048 + kh * 512);
        acc = __builtin_amdgcn_mfma_f32_32x32x16_f16(ka, qf[kh], acc, 0, 0, 0);
      }
      // ---- softmax + PV, lane-local: frag f = 2*kb + a uses regs 8a..8a+7 ----
#pragma unroll
      for (int a = 0; a < 2; ++a) {
        union { _Float16 h[8]; f16x8_t v; f16x2_t p2[4]; } F;
#pragma unroll
        for (int idx = 0; idx < 8; ++idx) {
          float x = acc[8 * a + idx];
          if (has_mask) x = __builtin_fmaf(mk[kb][a][idx >> 2][idx & 3], LOG2E, x);
          F.h[idx] = (_Float16)EXP2F(x);
        }
#pragma unroll
        for (int t = 0; t < 4; ++t) lacc = rowsum2(F.p2[t], lacc);
        const int f = kb * 2 + a;
        const f16x8_t v0 = *(const f16x8_t*)(vtile + f * 1024);
        o0 = __builtin_amdgcn_mfma_f32_32x32x16_f16(F.v, v0, o0, 0, 0, 0);
        const f16x8_t v1 = *(const f16x8_t*)(vtile + f * 1024 + 512);
        o1 = __builtin_amdgcn_mfma_f32_32x32x16_f16(F.v, v1, o1, 0, 0, 0);
      }
    }
    ktile += 4096;
    vtile += 4096;
  }

  // ---- epilogue ----
  float lq = lacc + __shfl_xor(lacc, 32);
  if constexpr (NS > 1) {
    float* op = Opart + (size_t)part * (16 * 4096 * 64) + hoff;
#pragma unroll
    for (int r2 = 0; r2 < 4; ++r2) {
#pragma unroll
      for (int rr = 0; rr < 4; ++rr) {
        const int reg  = r2 * 4 + rr;
        const int qrow = rr + 8 * r2 + 4 * h2;      // C/D row mapping (m74/m101)
        const size_t row = (size_t)(qt * 128 + w * 32 + qrow) * 64;
        op[row + n]      = o0[reg];
        op[row + 32 + n] = o1[reg];
      }
    }
    if (h2 == 0)
      Lpart[(size_t)part * 65536 + (size_t)hh * 4096 + qcol] = lq;
  } else {
    float* op = Og + hoff;
#pragma unroll
    for (int r2 = 0; r2 < 4; ++r2) {
#pragma unroll
      for (int rr = 0; rr < 4; ++rr) {
        const int reg  = r2 * 4 + rr;
        const int qrow = rr + 8 * r2 + 4 * h2;      // C/D row mapping (m74/m101)
        float lr  = __shfl(lq, qrow);
        float inv = 1.0f / lr;
        const size_t row = (size_t)(qt * 128 + w * 32 + qrow) * 64;
        op[row + n]      = o0[reg] * inv;
        op[row + 32 + n] = o1[reg] * inv;
      }
    }
  }
}

// ---------------- fallback (no workspace): round-6 proven LDS body ----------------
__launch_bounds__(256, 2)
__global__ void sdpa_lds_fallback(const float* __restrict__ Qg, const float* __restrict__ Kg,
                                  const float* __restrict__ Vg, const float* __restrict__ Mg,
                                  float* __restrict__ Og, const int* __restrict__ flag) {
  __shared__ __align__(16) _Float16 Ks[64 * 72];   // [key][feat]
  __shared__ __align__(16) _Float16 Vt[64 * 72];   // [feat][key]

  const int tid  = threadIdx.x;
  const int bid  = blockIdx.x;
  const int hh   = ((bid & 7) << 1) | ((bid >> 3) & 1);
  const int qt   = bid >> 4;
  const int w    = tid >> 6;
  const int lane = tid & 63;
  const int n    = lane & 31;
  const int h2   = lane >> 5;
  const int sig  = sigf(n);
  const bool has_mask = (*flag) != 0;

  const size_t hoff = (size_t)hh * 4096 * 64;
  const int qcol = qt * 128 + w * 32 + n;

  f16x8_t qf[4];
  {
    const float* qp = Qg + hoff + (size_t)qcol * 64 + 8 * h2;
#pragma unroll
    for (int kh = 0; kh < 4; ++kh) {
      f32x4_t a = *(const f32x4_t*)(qp + kh * 16);
      f32x4_t b = *(const f32x4_t*)(qp + kh * 16 + 4);
      union { _Float16 h[8]; f16x8_t v; } U;
#pragma unroll
      for (int j = 0; j < 4; ++j) { U.h[j] = (_Float16)(a[j] * QSCALE); U.h[4 + j] = (_Float16)(b[j] * QSCALE); }
      qf[kh] = U.v;
    }
  }

  f32x16_t o0 = {0.f,0.f,0.f,0.f,0.f,0.f,0.f,0.f,0.f,0.f,0.f,0.f,0.f,0.f,0.f,0.f};
  f32x16_t o1 = o0;
  float lacc = 0.0f;

#pragma unroll 1
  for (int kt = 0; kt < 64; ++kt) {
    const int kbase = kt * 64;
    f32x4_t k0, k1, k2, k3;
    float vlo[8], vhi[8];
    {
      const float* kp = Kg + hoff + (size_t)(kbase + (tid >> 2)) * 64 + (tid & 3) * 16;
      k0 = *(const f32x4_t*)(kp + 0);
      k1 = *(const f32x4_t*)(kp + 4);
      k2 = *(const f32x4_t*)(kp + 8);
      k3 = *(const f32x4_t*)(kp + 12);
      const float* vp = Vg + hoff + (size_t)(kbase + (tid >> 5) * 8) * 64 + (tid & 31);
#pragma unroll
      for (int j = 0; j < 8; ++j) {
        vlo[j] = vp[(size_t)j * 64];
        vhi[j] = vp[(size_t)j * 64 + 32];
      }
    }
    f32x4_t mk[2][2][2];
    if (has_mask) {
      const float* mp = Mg + (size_t)qcol * 4096 + kbase + 8 * h2;
#pragma unroll
      for (int kb = 0; kb < 2; ++kb)
#pragma unroll
        for (int a = 0; a < 2; ++a)
#pragma unroll
          for (int b = 0; b < 2; ++b)
            mk[kb][a][b] = *(const f32x4_t*)(mp + kb * 32 + 16 * a + 4 * b);
    }

    __syncthreads();
    {
      union { _Float16 h[8]; uint4 q; } A, B;
#pragma unroll
      for (int j = 0; j < 4; ++j) {
        A.h[j] = (_Float16)k0[j];  A.h[4 + j] = (_Float16)k1[j];
        B.h[j] = (_Float16)k2[j];  B.h[4 + j] = (_Float16)k3[j];
      }
      *(uint4*)&Ks[(tid >> 2) * 72 + (tid & 3) * 16]     = A.q;
      *(uint4*)&Ks[(tid >> 2) * 72 + (tid & 3) * 16 + 8] = B.q;
      union { _Float16 h[8]; uint4 q; } C, D;
#pragma unroll
      for (int j = 0; j < 8; ++j) { C.h[j] = (_Float16)vlo[j]; D.h[j] = (_Float16)vhi[j]; }
      *(uint4*)&Vt[(tid & 31) * 72 + (tid >> 5) * 8]        = C.q;
      *(uint4*)&Vt[((tid & 31) + 32) * 72 + (tid >> 5) * 8] = D.q;
    }
    __syncthreads();

#pragma unroll
    for (int kb = 0; kb < 2; ++kb) {
      f32x16_t acc = {0.f,0.f,0.f,0.f,0.f,0.f,0.f,0.f,0.f,0.f,0.f,0.f,0.f,0.f,0.f,0.f};
#pragma unroll
      for (int kh = 0; kh < 4; ++kh) {
        const f16x8_t ka = *(const f16x8_t*)&Ks[(kb * 32 + sig) * 72 + kh * 16 + 8 * h2];
        acc = __builtin_amdgcn_mfma_f32_32x32x16_f16(ka, qf[kh], acc, 0, 0, 0);
      }
#pragma unroll
      for (int a = 0; a < 2; ++a) {
        union { _Float16 h[8]; f16x8_t v; f16x2_t p2[4]; } F;
#pragma unroll
        for (int idx = 0; idx < 8; ++idx) {
          float x = acc[8 * a + idx];
          if (has_mask) x = __builtin_fmaf(mk[kb][a][idx >> 2][idx & 3], LOG2E, x);
          F.h[idx] = (_Float16)EXP2F(x);
        }
#pragma unroll
        for (int t = 0; t < 4; ++t) lacc = rowsum2(F.p2[t], lacc);
        const int f = kb * 2 + a;
        const f16x8_t v0 = *(const f16x8_t*)&Vt[n * 72 + f * 16 + 8 * h2];
        o0 = __builtin_amdgcn_mfma_f32_32x32x16_f16(F.v, v0, o0, 0, 0, 0);
        const f16x8_t v1 = *(const f16x8_t*)&Vt[(32 + n) * 72 + f * 16 + 8 * h2];
        o1 = __builtin_amdgcn_mfma_f32_32x32x16_f16(F.v, v1, o1, 0, 0, 0);
      }
    }
  }

  float lq = lacc + __shfl_xor(lacc, 32);
  float* op = Og + hoff;
#pragma unroll
  for (int r2 = 0; r2 < 4; ++r2) {
#pragma unroll
    for (int rr = 0; rr < 4; ++rr) {
      const int reg  = r2 * 4 + rr;
      const int qrow = rr + 8 * r2 + 4 * h2;
      float lr  = __shfl(lq, qrow);
      float inv = 1.0f / lr;
      const size_t row = (size_t)(qt * 128 + w * 32 + qrow) * 64;
      op[row + n]      = o0[reg] * inv;
      op[row + 32 + n] = o1[reg] * inv;
    }
  }
}

// ---------------- combine: O = (sum_p O_p) / (sum_p l_p) ----------------
template <int NS>
__global__ void combine_kernel(const float* __restrict__ Opart, const float* __restrict__ Lpart,
                               float* __restrict__ Og) {
  const size_t NELEM = (size_t)16 * 4096 * 64;
  const size_t e   = ((size_t)blockIdx.x * 256 + threadIdx.x) * 8;
  const size_t row = e >> 6;
  float lsum = 0.0f;
#pragma unroll
  for (int p = 0; p < NS; ++p) lsum += Lpart[(size_t)p * 65536 + row];
  const float inv = 1.0f / lsum;
  f32x4_t s0 = {0.f, 0.f, 0.f, 0.f}, s1 = s0;
#pragma unroll
  for (int p = 0; p < NS; ++p) {
    const float* a = Opart + (size_t)p * NELEM + e;
    f32x4_t x0 = *(const f32x4_t*)a;
    f32x4_t x1 = *(const f32x4_t*)(a + 4);
#pragma unroll
    for (int j = 0; j < 4; ++j) { s0[j] += x0[j]; s1[j] += x1[j]; }
  }
  f32x4_t r0, r1;
#pragma unroll
  for (int j = 0; j < 4; ++j) { r0[j] = s0[j] * inv; r1[j] = s1[j] * inv; }
  *(f32x4_t*)(Og + e)     = r0;
  *(f32x4_t*)(Og + e + 4) = r1;
}

extern "C" void kernel_launch(void* const* d_in, const int* in_sizes, int n_in,
                              void* d_out, int out_size, void* d_ws, size_t ws_size,
                              hipStream_t stream) {
  const float* Q = (const float*)d_in[0];
  const float* K = (const float*)d_in[1];
  const float* V = (const float*)d_in[2];
  const float* M = (const float*)d_in[3];
  float* O = (float*)d_out;

  const size_t NELEM = (size_t)16 * 4096 * 64;          // 4M per tensor
  const size_t need16 = 256 + 2 * NELEM * sizeof(_Float16);                  // Kf + Vf
  const size_t need2  = need16 + 2 * NELEM * sizeof(float) + 2 * 65536 * sizeof(float);
  const size_t need4  = need16 + 4 * NELEM * sizeof(float) + 4 * 65536 * sizeof(float);
  int* flag = (int*)d_ws;
  const bool ws16 = (ws_size >= need16);
  _Float16* Kf    = ws16 ? (_Float16*)((char*)d_ws + 256) : nullptr;
  _Float16* Vf    = ws16 ? Kf + NELEM : nullptr;
  float*    Opart = ws16 ? (float*)(Vf + NELEM) : nullptr;
  float*    Lpart4 = ws16 ? Opart + 4 * NELEM : nullptr;
  float*    Lpart2 = ws16 ? Opart + 2 * NELEM : nullptr;

  hipMemsetAsync(flag, 0, sizeof(int), stream);
  prep_kernel<<<2048, 256, 0, stream>>>(M, K, V, Kf, Vf, flag);

  if (ws_size >= need4) {
    sdpa_direct<4><<<2048, 256, 0, stream>>>(Q, M, Kf, Vf, O, Opart, Lpart4, flag);
    combine_kernel<4><<<2048, 256, 0, stream>>>(Opart, Lpart4, O);
  } else if (ws_size >= need2) {
    sdpa_direct<2><<<1024, 256, 0, stream>>>(Q, M, Kf, Vf, O, Opart, Lpart2, flag);
    combine_kernel<2><<<2048, 256, 0, stream>>>(Opart, Lpart2, O);
  } else if (ws16) {
    sdpa_direct<1><<<512, 256, 0, stream>>>(Q, M, Kf, Vf, O, nullptr, nullptr, flag);
  } else {
    sdpa_lds_fallback<<<512, 256, 0, stream>>>(Q, K, V, M, O, flag);
  }
}

// Round 8
// 232.332 us; speedup vs baseline: 1.2534x; 1.2534x over previous
//
#include <hip/hip_runtime.h>
#include <stdint.h>

#define LOG2E  1.44269504088896f
#define QSCALE (0.125f * LOG2E)   // folded into Q: sacc is already the exp2 argument

typedef float    f32x4_t  __attribute__((ext_vector_type(4)));
typedef float    f32x16_t __attribute__((ext_vector_type(16)));
typedef _Float16 f16x8_t  __attribute__((ext_vector_type(8)));
typedef _Float16 f16x2_t  __attribute__((ext_vector_type(2)));

#if __has_builtin(__builtin_amdgcn_exp2f)
#define EXP2F(x) __builtin_amdgcn_exp2f(x)
#else
#define EXP2F(x) exp2f(x)
#endif

__device__ __forceinline__ float rowsum2(f16x2_t p, float acc) {
#if __has_builtin(__builtin_amdgcn_fdot2)
  return __builtin_amdgcn_fdot2(p, (f16x2_t){(_Float16)1.0f, (_Float16)1.0f}, acc, false);
#else
  return acc + (float)p[0] + (float)p[1];
#endif
}

// ---------------- fused prep: mask scan + K f32->f16 + V transpose ----------------
// grid 2048 x 256. Blocks 0..2047: mask chunk + K-convert chunk. Blocks 0..1023: one V tile.
// One launch replaces the original 3 prep kernels (~35us -> ~18us device).
__global__ void prep_kernel(const float* __restrict__ M, const float* __restrict__ K,
                            const float* __restrict__ V, _Float16* __restrict__ Kh,
                            _Float16* __restrict__ Vth, int* __restrict__ flag) {
  __shared__ __align__(16) _Float16 T[64 * 72];
  const int tid = threadIdx.x;
  const int bid = blockIdx.x;

  // -- mask all-zero scan (67 MB total) --
  {
    const float* p = M + (size_t)bid * 8192 + (size_t)tid * 4;
    unsigned acc = 0;
#pragma unroll
    for (int i = 0; i < 8; ++i) {
      f32x4_t v = *(const f32x4_t*)(p + (size_t)i * 1024);
      acc |= __float_as_uint(v[0]) | __float_as_uint(v[1]) |
             __float_as_uint(v[2]) | __float_as_uint(v[3]);
    }
    if (acc & 0x7fffffffu) atomicOr(flag, 1);
  }

  if (Kh != nullptr) {
    // -- K f32 -> f16 (8 elems/thread) --
    {
      const size_t idx = ((size_t)bid * 256 + tid) * 8;
      f32x4_t a = *(const f32x4_t*)(K + idx);
      f32x4_t b = *(const f32x4_t*)(K + idx + 4);
      union { _Float16 h[8]; uint4 q; } U;
#pragma unroll
      for (int j = 0; j < 4; ++j) { U.h[j] = (_Float16)a[j]; U.h[4 + j] = (_Float16)b[j]; }
      *(uint4*)(Kh + idx) = U.q;
    }
    // -- V transpose to [head][feat][seq] f16, one 64x64 tile per block (blocks 0..1023) --
    if (bid < 1024) {
      const int head = bid >> 6;
      const int st   = bid & 63;
      const size_t hoff = (size_t)head * 4096 * 64;
      const int sl    = tid >> 2;
      const int fbase = (tid & 3) * 16;
      const float* src = V + hoff + (size_t)(st * 64 + sl) * 64 + fbase;
#pragma unroll
      for (int c = 0; c < 4; ++c) {
        f32x4_t a = *(const f32x4_t*)(src + c * 4);
#pragma unroll
        for (int j = 0; j < 4; ++j) T[(fbase + c * 4 + j) * 72 + sl] = (_Float16)a[j];
      }
      __syncthreads();
      const int feat = tid >> 2;
      const int sb   = (tid & 3) * 16;
      uint4 r0 = *(const uint4*)&T[feat * 72 + sb];
      uint4 r1 = *(const uint4*)&T[feat * 72 + sb + 8];
      _Float16* dst = Vth + hoff + (size_t)feat * 4096 + st * 64 + sb;
      *(uint4*)(dst)     = r0;
      *(uint4*)(dst + 8) = r1;
    }
  }
}

// ---------------- SDPA core: the proven round-0/2/6 body, NS=1 ----------------
// sigma trick: reading K rows through sig(n)=swap(bit2,bit3 of n) during S^T=K.Q^T
// relabels C-rows so that PV A-fragments are lane-local sacc regs (no P LDS round-trip).
// Structure notes from rounds 1-7 (do not re-try):
//  - in-flight staging regs across compute -> scratch spill (VGPR cliff at ~60+acc)
//  - KVB=128 / dbuf LDS -> spill + bank conflicts
//  - no-LDS fragment-direct -> latency-bound (LDS IS the latency hider)
//  - split-K: sdpa -7..-8.5us but combine costs +11..+20us -> net loss
template <bool WS16>
__launch_bounds__(256, 2)
__global__ void sdpa_kernel(const float* __restrict__ Qg, const float* __restrict__ Kg,
                            const float* __restrict__ Vg, const float* __restrict__ Mg,
                            const _Float16* __restrict__ Kh, const _Float16* __restrict__ Vth,
                            float* __restrict__ Og, const int* __restrict__ flag) {
  __shared__ __align__(16) _Float16 Ks[64 * 72];   // [key][feat]
  __shared__ __align__(16) _Float16 Vt[64 * 72];   // [feat][key]

  const int tid  = threadIdx.x;
  const int bid  = blockIdx.x;
  const int hh   = ((bid & 7) << 1) | ((bid >> 3) & 1);   // 2 heads per XCD (bid%8 -> XCD)
  const int qt   = bid >> 4;
  const int w    = tid >> 6;
  const int lane = tid & 63;
  const int n    = lane & 31;
  const int h2   = lane >> 5;
  const int sig  = (n & 0x13) | ((n >> 1) & 4) | ((n << 1) & 8);  // swap bits 2,3
  const bool has_mask = (*flag) != 0;

  const size_t hoff = (size_t)hh * 4096 * 64;
  const int qcol = qt * 128 + w * 32 + n;

  // ---- Q B-fragment straight from f32 (read once per block; no pre-convert pass) ----
  f16x8_t qf[4];
  {
    const float* qp = Qg + hoff + (size_t)qcol * 64 + 8 * h2;
#pragma unroll
    for (int kh = 0; kh < 4; ++kh) {
      f32x4_t a = *(const f32x4_t*)(qp + kh * 16);
      f32x4_t b = *(const f32x4_t*)(qp + kh * 16 + 4);
      union { _Float16 h[8]; f16x8_t v; } U;
#pragma unroll
      for (int j = 0; j < 4; ++j) { U.h[j] = (_Float16)(a[j] * QSCALE); U.h[4 + j] = (_Float16)(b[j] * QSCALE); }
      qf[kh] = U.v;
    }
  }

  f32x16_t o0 = {0.f,0.f,0.f,0.f,0.f,0.f,0.f,0.f,0.f,0.f,0.f,0.f,0.f,0.f,0.f,0.f};
  f32x16_t o1 = o0;
  float lacc = 0.0f;

#pragma unroll 1
  for (int kt = 0; kt < 64; ++kt) {
    const int kbase = kt * 64;

    // -- staging prefetch (global -> regs) --
    uint4 kk0, kk1, vv0, vv1;            // WS16 path
    f32x4_t k0, k1, k2, k3;              // fallback K
    float vlo[8], vhi[8];                // fallback V
    if (WS16) {
      const _Float16* kp = Kh + hoff + (size_t)(kbase + (tid >> 2)) * 64 + (tid & 3) * 16;
      kk0 = *(const uint4*)(kp);
      kk1 = *(const uint4*)(kp + 8);
      const _Float16* vp = Vth + hoff + (size_t)(tid >> 2) * 4096 + kbase + (tid & 3) * 16;
      vv0 = *(const uint4*)(vp);
      vv1 = *(const uint4*)(vp + 8);
    } else {
      const float* kp = Kg + hoff + (size_t)(kbase + (tid >> 2)) * 64 + (tid & 3) * 16;
      k0 = *(const f32x4_t*)(kp + 0);
      k1 = *(const f32x4_t*)(kp + 4);
      k2 = *(const f32x4_t*)(kp + 8);
      k3 = *(const f32x4_t*)(kp + 12);
      const float* vp = Vg + hoff + (size_t)(kbase + (tid >> 5) * 8) * 64 + (tid & 31);
#pragma unroll
      for (int j = 0; j < 8; ++j) {
        vlo[j] = vp[(size_t)j * 64];
        vhi[j] = vp[(size_t)j * 64 + 32];
      }
    }

    // -- mask tile: element (kb, reg=8a+4b+c) -> key kb*32 + 16a + 8*h2 + 4b + c --
    f32x4_t mk[2][2][2];
    if (has_mask) {
      const float* mp = Mg + (size_t)qcol * 4096 + kbase + 8 * h2;
#pragma unroll
      for (int kb = 0; kb < 2; ++kb)
#pragma unroll
        for (int a = 0; a < 2; ++a)
#pragma unroll
          for (int b = 0; b < 2; ++b)
            mk[kb][a][b] = *(const f32x4_t*)(mp + kb * 32 + 16 * a + 4 * b);
    }

    __syncthreads();   // prior iteration's LDS reads complete before overwrite

    if (WS16) {
      *(uint4*)&Ks[(tid >> 2) * 72 + (tid & 3) * 16]     = kk0;
      *(uint4*)&Ks[(tid >> 2) * 72 + (tid & 3) * 16 + 8] = kk1;
      *(uint4*)&Vt[(tid >> 2) * 72 + (tid & 3) * 16]     = vv0;
      *(uint4*)&Vt[(tid >> 2) * 72 + (tid & 3) * 16 + 8] = vv1;
    } else {
      union { _Float16 h[8]; uint4 q; } A, B;
#pragma unroll
      for (int j = 0; j < 4; ++j) {
        A.h[j] = (_Float16)k0[j];  A.h[4 + j] = (_Float16)k1[j];
        B.h[j] = (_Float16)k2[j];  B.h[4 + j] = (_Float16)k3[j];
      }
      *(uint4*)&Ks[(tid >> 2) * 72 + (tid & 3) * 16]     = A.q;
      *(uint4*)&Ks[(tid >> 2) * 72 + (tid & 3) * 16 + 8] = B.q;
      union { _Float16 h[8]; uint4 q; } C, D;
#pragma unroll
      for (int j = 0; j < 8; ++j) { C.h[j] = (_Float16)vlo[j]; D.h[j] = (_Float16)vhi[j]; }
      *(uint4*)&Vt[(tid & 31) * 72 + (tid >> 5) * 8]        = C.q;
      *(uint4*)&Vt[((tid & 31) + 32) * 72 + (tid >> 5) * 8] = D.q;
    }

    __syncthreads();   // staging visible to all waves

#pragma unroll
    for (int kb = 0; kb < 2; ++kb) {
      // ---- S^T = K.Q^T with sigma-permuted A rows ----
      f32x16_t acc = {0.f,0.f,0.f,0.f,0.f,0.f,0.f,0.f,0.f,0.f,0.f,0.f,0.f,0.f,0.f,0.f};
#pragma unroll
      for (int kh = 0; kh < 4; ++kh) {
        const f16x8_t ka = *(const f16x8_t*)&Ks[(kb * 32 + sig) * 72 + kh * 16 + 8 * h2];
        acc = __builtin_amdgcn_mfma_f32_32x32x16_f16(ka, qf[kh], acc, 0, 0, 0);
      }
      // ---- softmax + PV, lane-local: frag f = 2*kb + a uses regs 8a..8a+7 ----
#pragma unroll
      for (int a = 0; a < 2; ++a) {
        union { _Float16 h[8]; f16x8_t v; f16x2_t p2[4]; } F;
#pragma unroll
        for (int idx = 0; idx < 8; ++idx) {
          float x = acc[8 * a + idx];
          if (has_mask) x = __builtin_fmaf(mk[kb][a][idx >> 2][idx & 3], LOG2E, x);
          F.h[idx] = (_Float16)EXP2F(x);
        }
#pragma unroll
        for (int t = 0; t < 4; ++t) lacc = rowsum2(F.p2[t], lacc);
        const int f = kb * 2 + a;
        const f16x8_t v0 = *(const f16x8_t*)&Vt[n * 72 + f * 16 + 8 * h2];
        o0 = __builtin_amdgcn_mfma_f32_32x32x16_f16(F.v, v0, o0, 0, 0, 0);
        const f16x8_t v1 = *(const f16x8_t*)&Vt[(32 + n) * 72 + f * 16 + 8 * h2];
        o1 = __builtin_amdgcn_mfma_f32_32x32x16_f16(F.v, v1, o1, 0, 0, 0);
      }
    }
  }

  // ---- epilogue: l per q-column, normalize, store ----
  float lq = lacc + __shfl_xor(lacc, 32);
  float* op = Og + hoff;
#pragma unroll
  for (int r2 = 0; r2 < 4; ++r2) {
#pragma unroll
    for (int rr = 0; rr < 4; ++rr) {
      const int reg  = r2 * 4 + rr;
      const int qrow = rr + 8 * r2 + 4 * h2;      // C/D row mapping (m74/m101)
      float lr  = __shfl(lq, qrow);
      float inv = 1.0f / lr;
      const size_t row = (size_t)(qt * 128 + w * 32 + qrow) * 64;
      op[row + n]      = o0[reg] * inv;
      op[row + 32 + n] = o1[reg] * inv;
    }
  }
}

extern "C" void kernel_launch(void* const* d_in, const int* in_sizes, int n_in,
                              void* d_out, int out_size, void* d_ws, size_t ws_size,
                              hipStream_t stream) {
  const float* Q = (const float*)d_in[0];
  const float* K = (const float*)d_in[1];
  const float* V = (const float*)d_in[2];
  const float* M = (const float*)d_in[3];
  float* O = (float*)d_out;

  const size_t NELEM  = (size_t)16 * 4096 * 64;         // 4M per tensor
  const size_t need16 = 256 + 2 * NELEM * sizeof(_Float16);   // Kh + Vth
  int* flag = (int*)d_ws;
  const bool ws16 = (ws_size >= need16);
  _Float16* Kh  = ws16 ? (_Float16*)((char*)d_ws + 256) : nullptr;
  _Float16* Vth = ws16 ? Kh + NELEM : nullptr;

  hipMemsetAsync(flag, 0, sizeof(int), stream);
  prep_kernel<<<2048, 256, 0, stream>>>(M, K, V, Kh, Vth, flag);

  if (ws16) {
    sdpa_kernel<true><<<512, 256, 0, stream>>>(Q, K, V, M, Kh, Vth, O, flag);
  } else {
    sdpa_kernel<false><<<512, 256, 0, stream>>>(Q, K, V, M, nullptr, nullptr, O, flag);
  }
}

// Round 9
// 227.184 us; speedup vs baseline: 1.2818x; 1.0227x over previous
//
#include <hip/hip_runtime.h>
#include <stdint.h>

#define LOG2E  1.44269504088896f
#define QSCALE (0.125f * LOG2E)   // folded into Q: sacc is already the exp2 argument

typedef float    f32x4_t  __attribute__((ext_vector_type(4)));
typedef float    f32x16_t __attribute__((ext_vector_type(16)));
typedef _Float16 f16x8_t  __attribute__((ext_vector_type(8)));
typedef _Float16 f16x2_t  __attribute__((ext_vector_type(2)));

#if __has_builtin(__builtin_amdgcn_exp2f)
#define EXP2F(x) __builtin_amdgcn_exp2f(x)
#else
#define EXP2F(x) exp2f(x)
#endif

__device__ __forceinline__ float rowsum2(f16x2_t p, float acc) {
#if __has_builtin(__builtin_amdgcn_fdot2)
  return __builtin_amdgcn_fdot2(p, (f16x2_t){(_Float16)1.0f, (_Float16)1.0f}, acc, false);
#else
  return acc + (float)p[0] + (float)p[1];
#endif
}

// ---------------- fused prep: mask scan + K f32->f16 + V transpose ----------------
// grid 2048 x 256. Blocks 0..2047: mask chunk + K-convert chunk. Blocks 0..1023: one V tile.
__global__ void prep_kernel(const float* __restrict__ M, const float* __restrict__ K,
                            const float* __restrict__ V, _Float16* __restrict__ Kh,
                            _Float16* __restrict__ Vth, int* __restrict__ flag) {
  __shared__ __align__(16) _Float16 T[64 * 72];
  const int tid = threadIdx.x;
  const int bid = blockIdx.x;

  // -- mask all-zero scan (67 MB total) --
  {
    const float* p = M + (size_t)bid * 8192 + (size_t)tid * 4;
    unsigned acc = 0;
#pragma unroll
    for (int i = 0; i < 8; ++i) {
      f32x4_t v = *(const f32x4_t*)(p + (size_t)i * 1024);
      acc |= __float_as_uint(v[0]) | __float_as_uint(v[1]) |
             __float_as_uint(v[2]) | __float_as_uint(v[3]);
    }
    if (acc & 0x7fffffffu) atomicOr(flag, 1);
  }

  if (Kh != nullptr) {
    // -- K f32 -> f16 (8 elems/thread) --
    {
      const size_t idx = ((size_t)bid * 256 + tid) * 8;
      f32x4_t a = *(const f32x4_t*)(K + idx);
      f32x4_t b = *(const f32x4_t*)(K + idx + 4);
      union { _Float16 h[8]; uint4 q; } U;
#pragma unroll
      for (int j = 0; j < 4; ++j) { U.h[j] = (_Float16)a[j]; U.h[4 + j] = (_Float16)b[j]; }
      *(uint4*)(Kh + idx) = U.q;
    }
    // -- V transpose to [head][feat][seq] f16, one 64x64 tile per block (blocks 0..1023) --
    if (bid < 1024) {
      const int head = bid >> 6;
      const int st   = bid & 63;
      const size_t hoff = (size_t)head * 4096 * 64;
      const int sl    = tid >> 2;
      const int fbase = (tid & 3) * 16;
      const float* src = V + hoff + (size_t)(st * 64 + sl) * 64 + fbase;
#pragma unroll
      for (int c = 0; c < 4; ++c) {
        f32x4_t a = *(const f32x4_t*)(src + c * 4);
#pragma unroll
        for (int j = 0; j < 4; ++j) T[(fbase + c * 4 + j) * 72 + sl] = (_Float16)a[j];
      }
      __syncthreads();
      const int feat = tid >> 2;
      const int sb   = (tid & 3) * 16;
      uint4 r0 = *(const uint4*)&T[feat * 72 + sb];
      uint4 r1 = *(const uint4*)&T[feat * 72 + sb + 8];
      _Float16* dst = Vth + hoff + (size_t)feat * 4096 + st * 64 + sb;
      *(uint4*)(dst)     = r0;
      *(uint4*)(dst + 8) = r1;
    }
  }
}

// ---------------- SDPA: intra-block split-K, 512 threads ----------------
// Waves 0-3: K-half 0 into Ks[0]/Vt[0]; waves 4-7: K-half 1 into Ks[1]/Vt[1]; same
// 128 q-cols. Inner body byte-identical to the proven r8 loop (VGPR cliff: no new
// live state). Partials merge via one LDS round-trip over the dead staging buffers
// (no online softmax -> (o,l) combine is a pure add), replacing r2/r6's 33MB global
// combine. 2 blocks/CU x 8 waves = 4 waves/SIMD = r6's measured-faster regime,
// with HALF the barriers per wave (32 tiles, not 64).
__launch_bounds__(512, 2)
__global__ void sdpa_split(const float* __restrict__ Qg, const float* __restrict__ Mg,
                           const _Float16* __restrict__ Kh, const _Float16* __restrict__ Vth,
                           float* __restrict__ Og, const int* __restrict__ flag) {
  __shared__ __align__(16) _Float16 Ks[2][64 * 72];   // [khalf][key][feat]
  __shared__ __align__(16) _Float16 Vt[2][64 * 72];   // [khalf][feat][key]

  const int tid   = threadIdx.x;
  const int bid   = blockIdx.x;
  const int khalf = tid >> 8;         // 0: tiles 0..31, 1: tiles 32..63
  const int ht    = tid & 255;        // thread id within half
  const int hh    = ((bid & 7) << 1) | ((bid >> 3) & 1);   // 2 heads per XCD
  const int qt    = bid >> 4;
  const int w     = ht >> 6;
  const int lane  = tid & 63;
  const int n     = lane & 31;
  const int h2    = lane >> 5;
  const int sig   = (n & 0x13) | ((n >> 1) & 4) | ((n << 1) & 8);  // swap bits 2,3
  const bool has_mask = (*flag) != 0;

  const size_t hoff = (size_t)hh * 4096 * 64;
  const int qcol = qt * 128 + w * 32 + n;
  const int ktlo = khalf * 32;

  // ---- Q B-fragment straight from f32 (each half reads the same Q; L2-hit) ----
  f16x8_t qf[4];
  {
    const float* qp = Qg + hoff + (size_t)qcol * 64 + 8 * h2;
#pragma unroll
    for (int kh = 0; kh < 4; ++kh) {
      f32x4_t a = *(const f32x4_t*)(qp + kh * 16);
      f32x4_t b = *(const f32x4_t*)(qp + kh * 16 + 4);
      union { _Float16 h[8]; f16x8_t v; } U;
#pragma unroll
      for (int j = 0; j < 4; ++j) { U.h[j] = (_Float16)(a[j] * QSCALE); U.h[4 + j] = (_Float16)(b[j] * QSCALE); }
      qf[kh] = U.v;
    }
  }

  f32x16_t o0 = {0.f,0.f,0.f,0.f,0.f,0.f,0.f,0.f,0.f,0.f,0.f,0.f,0.f,0.f,0.f,0.f};
  f32x16_t o1 = o0;
  float lacc = 0.0f;

#pragma unroll 1
  for (int kk = 0; kk < 32; ++kk) {
    const int kbase = (ktlo + kk) * 64;

    // -- staging prefetch (global -> regs), r8-proven order --
    uint4 kk0, kk1, vv0, vv1;
    {
      const _Float16* kp = Kh + hoff + (size_t)(kbase + (ht >> 2)) * 64 + (ht & 3) * 16;
      kk0 = *(const uint4*)(kp);
      kk1 = *(const uint4*)(kp + 8);
      const _Float16* vp = Vth + hoff + (size_t)(ht >> 2) * 4096 + kbase + (ht & 3) * 16;
      vv0 = *(const uint4*)(vp);
      vv1 = *(const uint4*)(vp + 8);
    }

    // -- mask tile: element (kb, reg=8a+4b+c) -> key kb*32 + 16a + 8*h2 + 4b + c --
    f32x4_t mk[2][2][2];
    if (has_mask) {
      const float* mp = Mg + (size_t)qcol * 4096 + kbase + 8 * h2;
#pragma unroll
      for (int kb = 0; kb < 2; ++kb)
#pragma unroll
        for (int a = 0; a < 2; ++a)
#pragma unroll
          for (int b = 0; b < 2; ++b)
            mk[kb][a][b] = *(const f32x4_t*)(mp + kb * 32 + 16 * a + 4 * b);
    }

    __syncthreads();   // prior iteration's LDS reads complete before overwrite

    *(uint4*)&Ks[khalf][(ht >> 2) * 72 + (ht & 3) * 16]     = kk0;
    *(uint4*)&Ks[khalf][(ht >> 2) * 72 + (ht & 3) * 16 + 8] = kk1;
    *(uint4*)&Vt[khalf][(ht >> 2) * 72 + (ht & 3) * 16]     = vv0;
    *(uint4*)&Vt[khalf][(ht >> 2) * 72 + (ht & 3) * 16 + 8] = vv1;

    __syncthreads();   // staging visible to all waves

#pragma unroll
    for (int kb = 0; kb < 2; ++kb) {
      // ---- S^T = K.Q^T with sigma-permuted A rows ----
      f32x16_t acc = {0.f,0.f,0.f,0.f,0.f,0.f,0.f,0.f,0.f,0.f,0.f,0.f,0.f,0.f,0.f,0.f};
#pragma unroll
      for (int kh = 0; kh < 4; ++kh) {
        const f16x8_t ka = *(const f16x8_t*)&Ks[khalf][(kb * 32 + sig) * 72 + kh * 16 + 8 * h2];
        acc = __builtin_amdgcn_mfma_f32_32x32x16_f16(ka, qf[kh], acc, 0, 0, 0);
      }
      // ---- softmax + PV, lane-local: frag f = 2*kb + a uses regs 8a..8a+7 ----
#pragma unroll
      for (int a = 0; a < 2; ++a) {
        union { _Float16 h[8]; f16x8_t v; f16x2_t p2[4]; } F;
#pragma unroll
        for (int idx = 0; idx < 8; ++idx) {
          float x = acc[8 * a + idx];
          if (has_mask) x = __builtin_fmaf(mk[kb][a][idx >> 2][idx & 3], LOG2E, x);
          F.h[idx] = (_Float16)EXP2F(x);
        }
#pragma unroll
        for (int t = 0; t < 4; ++t) lacc = rowsum2(F.p2[t], lacc);
        const int f = kb * 2 + a;
        const f16x8_t v0 = *(const f16x8_t*)&Vt[khalf][n * 72 + f * 16 + 8 * h2];
        o0 = __builtin_amdgcn_mfma_f32_32x32x16_f16(F.v, v0, o0, 0, 0, 0);
        const f16x8_t v1 = *(const f16x8_t*)&Vt[khalf][(32 + n) * 72 + f * 16 + 8 * h2];
        o1 = __builtin_amdgcn_mfma_f32_32x32x16_f16(F.v, v1, o1, 0, 0, 0);
      }
    }
  }

  // ---- merge halves via dead staging LDS (pure add: no online-softmax state) ----
  // Xo0 overlays Ks (4608 floats: 4096 for o0 + 256 for l), Xo1 overlays Vt (4096 for o1).
  float* const Xo0 = (float*)&Ks[0][0];
  float* const Xo1 = (float*)&Vt[0][0];
  float* const Xl  = Xo0 + 4096;

  __syncthreads();   // all waves done with staging LDS
  if (khalf == 1) {
#pragma unroll
    for (int reg = 0; reg < 16; ++reg) {
      Xo0[(w * 16 + reg) * 64 + lane] = o0[reg];   // lane-contiguous: conflict-free
      Xo1[(w * 16 + reg) * 64 + lane] = o1[reg];
    }
    Xl[w * 64 + lane] = lacc;
  }
  __syncthreads();
  if (khalf == 0) {
#pragma unroll
    for (int reg = 0; reg < 16; ++reg) {
      o0[reg] += Xo0[(w * 16 + reg) * 64 + lane];
      o1[reg] += Xo1[(w * 16 + reg) * 64 + lane];
    }
    lacc += Xl[w * 64 + lane];

    float lq = lacc + __shfl_xor(lacc, 32);
    float* op = Og + hoff;
#pragma unroll
    for (int r2 = 0; r2 < 4; ++r2) {
#pragma unroll
      for (int rr = 0; rr < 4; ++rr) {
        const int reg  = r2 * 4 + rr;
        const int qrow = rr + 8 * r2 + 4 * h2;      // C/D row mapping (m74/m101)
        float lr  = __shfl(lq, qrow);
        float inv = 1.0f / lr;
        const size_t row = (size_t)(qt * 128 + w * 32 + qrow) * 64;
        op[row + n]      = o0[reg] * inv;
        op[row + 32 + n] = o1[reg] * inv;
      }
    }
  }
}

// ---------------- fallback (no workspace): r8 proven 256-thread body ----------------
__launch_bounds__(256, 2)
__global__ void sdpa_fallback(const float* __restrict__ Qg, const float* __restrict__ Kg,
                              const float* __restrict__ Vg, const float* __restrict__ Mg,
                              float* __restrict__ Og, const int* __restrict__ flag) {
  __shared__ __align__(16) _Float16 Ks[64 * 72];
  __shared__ __align__(16) _Float16 Vt[64 * 72];

  const int tid  = threadIdx.x;
  const int bid  = blockIdx.x;
  const int hh   = ((bid & 7) << 1) | ((bid >> 3) & 1);
  const int qt   = bid >> 4;
  const int w    = tid >> 6;
  const int lane = tid & 63;
  const int n    = lane & 31;
  const int h2   = lane >> 5;
  const int sig  = (n & 0x13) | ((n >> 1) & 4) | ((n << 1) & 8);
  const bool has_mask = (*flag) != 0;

  const size_t hoff = (size_t)hh * 4096 * 64;
  const int qcol = qt * 128 + w * 32 + n;

  f16x8_t qf[4];
  {
    const float* qp = Qg + hoff + (size_t)qcol * 64 + 8 * h2;
#pragma unroll
    for (int kh = 0; kh < 4; ++kh) {
      f32x4_t a = *(const f32x4_t*)(qp + kh * 16);
      f32x4_t b = *(const f32x4_t*)(qp + kh * 16 + 4);
      union { _Float16 h[8]; f16x8_t v; } U;
#pragma unroll
      for (int j = 0; j < 4; ++j) { U.h[j] = (_Float16)(a[j] * QSCALE); U.h[4 + j] = (_Float16)(b[j] * QSCALE); }
      qf[kh] = U.v;
    }
  }

  f32x16_t o0 = {0.f,0.f,0.f,0.f,0.f,0.f,0.f,0.f,0.f,0.f,0.f,0.f,0.f,0.f,0.f,0.f};
  f32x16_t o1 = o0;
  float lacc = 0.0f;

#pragma unroll 1
  for (int kt = 0; kt < 64; ++kt) {
    const int kbase = kt * 64;
    f32x4_t k0, k1, k2, k3;
    float vlo[8], vhi[8];
    {
      const float* kp = Kg + hoff + (size_t)(kbase + (tid >> 2)) * 64 + (tid & 3) * 16;
      k0 = *(const f32x4_t*)(kp + 0);
      k1 = *(const f32x4_t*)(kp + 4);
      k2 = *(const f32x4_t*)(kp + 8);
      k3 = *(const f32x4_t*)(kp + 12);
      const float* vp = Vg + hoff + (size_t)(kbase + (tid >> 5) * 8) * 64 + (tid & 31);
#pragma unroll
      for (int j = 0; j < 8; ++j) {
        vlo[j] = vp[(size_t)j * 64];
        vhi[j] = vp[(size_t)j * 64 + 32];
      }
    }
    f32x4_t mk[2][2][2];
    if (has_mask) {
      const float* mp = Mg + (size_t)qcol * 4096 + kbase + 8 * h2;
#pragma unroll
      for (int kb = 0; kb < 2; ++kb)
#pragma unroll
        for (int a = 0; a < 2; ++a)
#pragma unroll
          for (int b = 0; b < 2; ++b)
            mk[kb][a][b] = *(const f32x4_t*)(mp + kb * 32 + 16 * a + 4 * b);
    }

    __syncthreads();
    {
      union { _Float16 h[8]; uint4 q; } A, B;
#pragma unroll
      for (int j = 0; j < 4; ++j) {
        A.h[j] = (_Float16)k0[j];  A.h[4 + j] = (_Float16)k1[j];
        B.h[j] = (_Float16)k2[j];  B.h[4 + j] = (_Float16)k3[j];
      }
      *(uint4*)&Ks[(tid >> 2) * 72 + (tid & 3) * 16]     = A.q;
      *(uint4*)&Ks[(tid >> 2) * 72 + (tid & 3) * 16 + 8] = B.q;
      union { _Float16 h[8]; uint4 q; } C, D;
#pragma unroll
      for (int j = 0; j < 8; ++j) { C.h[j] = (_Float16)vlo[j]; D.h[j] = (_Float16)vhi[j]; }
      *(uint4*)&Vt[(tid & 31) * 72 + (tid >> 5) * 8]        = C.q;
      *(uint4*)&Vt[((tid & 31) + 32) * 72 + (tid >> 5) * 8] = D.q;
    }
    __syncthreads();

#pragma unroll
    for (int kb = 0; kb < 2; ++kb) {
      f32x16_t acc = {0.f,0.f,0.f,0.f,0.f,0.f,0.f,0.f,0.f,0.f,0.f,0.f,0.f,0.f,0.f,0.f};
#pragma unroll
      for (int kh = 0; kh < 4; ++kh) {
        const f16x8_t ka = *(const f16x8_t*)&Ks[(kb * 32 + sig) * 72 + kh * 16 + 8 * h2];
        acc = __builtin_amdgcn_mfma_f32_32x32x16_f16(ka, qf[kh], acc, 0, 0, 0);
      }
#pragma unroll
      for (int a = 0; a < 2; ++a) {
        union { _Float16 h[8]; f16x8_t v; f16x2_t p2[4]; } F;
#pragma unroll
        for (int idx = 0; idx < 8; ++idx) {
          float x = acc[8 * a + idx];
          if (has_mask) x = __builtin_fmaf(mk[kb][a][idx >> 2][idx & 3], LOG2E, x);
          F.h[idx] = (_Float16)EXP2F(x);
        }
#pragma unroll
        for (int t = 0; t < 4; ++t) lacc = rowsum2(F.p2[t], lacc);
        const int f = kb * 2 + a;
        const f16x8_t v0 = *(const f16x8_t*)&Vt[n * 72 + f * 16 + 8 * h2];
        o0 = __builtin_amdgcn_mfma_f32_32x32x16_f16(F.v, v0, o0, 0, 0, 0);
        const f16x8_t v1 = *(const f16x8_t*)&Vt[(32 + n) * 72 + f * 16 + 8 * h2];
        o1 = __builtin_amdgcn_mfma_f32_32x32x16_f16(F.v, v1, o1, 0, 0, 0);
      }
    }
  }

  float lq = lacc + __shfl_xor(lacc, 32);
  float* op = Og + hoff;
#pragma unroll
  for (int r2 = 0; r2 < 4; ++r2) {
#pragma unroll
    for (int rr = 0; rr < 4; ++rr) {
      const int reg  = r2 * 4 + rr;
      const int qrow = rr + 8 * r2 + 4 * h2;
      float lr  = __shfl(lq, qrow);
      float inv = 1.0f / lr;
      const size_t row = (size_t)(qt * 128 + w * 32 + qrow) * 64;
      op[row + n]      = o0[reg] * inv;
      op[row + 32 + n] = o1[reg] * inv;
    }
  }
}

extern "C" void kernel_launch(void* const* d_in, const int* in_sizes, int n_in,
                              void* d_out, int out_size, void* d_ws, size_t ws_size,
                              hipStream_t stream) {
  const float* Q = (const float*)d_in[0];
  const float* K = (const float*)d_in[1];
  const float* V = (const float*)d_in[2];
  const float* M = (const float*)d_in[3];
  float* O = (float*)d_out;

  const size_t NELEM  = (size_t)16 * 4096 * 64;         // 4M per tensor
  const size_t need16 = 256 + 2 * NELEM * sizeof(_Float16);   // Kh + Vth
  int* flag = (int*)d_ws;
  const bool ws16 = (ws_size >= need16);
  _Float16* Kh  = ws16 ? (_Float16*)((char*)d_ws + 256) : nullptr;
  _Float16* Vth = ws16 ? Kh + NELEM : nullptr;

  hipMemsetAsync(flag, 0, sizeof(int), stream);
  prep_kernel<<<2048, 256, 0, stream>>>(M, K, V, Kh, Vth, flag);

  if (ws16) {
    sdpa_split<<<512, 512, 0, stream>>>(Q, M, Kh, Vth, O, flag);
  } else {
    sdpa_fallback<<<512, 256, 0, stream>>>(Q, K, V, M, O, flag);
  }
}